// Round 1
// baseline (263.769 us; speedup 1.0000x reference)
//
#include <hip/hip_runtime.h>

// Depthwise 3x3 conv (stride 1, pad 1), 2 filters per input channel,
// output channels interleaved [2c, 2c+1], + bias.
// x (32,192,56,56) f32; w1,w2 (C,9); bias (2C); out (32,384,56,56).
//
// Direct (no-LDS) version: each thread owns a 4-row x 4-col output tile of
// one (b,c) plane. It streams the 6 needed input rows from global (one
// aligned float4 + 2 edge scalars per row); vertical 3-row reuse happens in
// registers, horizontal/halo reuse is served by L1 (a plane is 12.5 KB --
// L1-resident; LDS staging + barrier was pure overhead). 256-thread blocks,
// no barrier -> up to 32 waves/CU of independent work keeps the HBM stream
// uninterrupted. 20 weight loads amortized over 16 output pixels.

#define BB 32
#define CC 192
#define HH 56
#define WW 56
#define W4 14            // float4 segments per row
#define RT 4             // output rows per thread
#define HQ (HH / RT)     // 14 row-quads per plane
#define TPP (W4 * HQ)    // 196 threads per plane
#define NSEG (BB * CC * TPP)  // 1,204,224 thread-tiles
#define TPB 256          // NSEG / TPB = 4704 exactly, no tail

typedef float f32x4 __attribute__((ext_vector_type(4)));

__global__ __launch_bounds__(TPB, 6) void dwconv2_direct_kernel(
    const float* __restrict__ x,
    const float* __restrict__ w1,
    const float* __restrict__ w2,
    const float* __restrict__ bias,
    float* __restrict__ out)
{
    const int idx = blockIdx.x * TPB + threadIdx.x;

    const int bc  = idx / TPP;        // (b*CC + c)
    const int rem = idx % TPP;
    const int hq  = rem / W4;
    const int w4  = rem % W4;
    const int h0  = hq * RT;          // first output row of this tile
    const int w0  = w4 * 4;           // first output col of this tile

    const float* __restrict__ plane = x + (size_t)bc * (HH * WW);
    const int c = bc % CC;

    // weights + bias to registers (L1/L2-resident: 13.8 KB total for all c)
    float a1[9], a2[9];
#pragma unroll
    for (int i = 0; i < 9; ++i) { a1[i] = w1[c * 9 + i]; a2[i] = w2[c * 9 + i]; }
    const float b1 = bias[2 * c], b2 = bias[2 * c + 1];

    float o1[RT][4], o2[RT][4];
#pragma unroll
    for (int p = 0; p < RT; ++p)
#pragma unroll
        for (int j = 0; j < 4; ++j) { o1[p][j] = b1; o2[p][j] = b2; }

    // Stream input rows ir = h0-1 .. h0+4. Input row r (local) feeds output
    // rows p = r-2 .. r (clamped to 0..RT-1) with tap row k = r - p.
#pragma unroll
    for (int r = 0; r < RT + 2; ++r) {
        const int ir = h0 - 1 + r;
        float rv[6];                       // image cols w0-1 .. w0+4
        if (ir >= 0 && ir < HH) {
            const float* rp = plane + ir * WW + w0;   // 16B-aligned
            const f32x4 m = *(const f32x4*)rp;
            rv[1] = m.x; rv[2] = m.y; rv[3] = m.z; rv[4] = m.w;
            rv[0] = (w4 > 0)      ? rp[-1] : 0.f;     // left halo col
            rv[5] = (w4 < W4 - 1) ? rp[4]  : 0.f;     // right halo col
        } else {
#pragma unroll
            for (int j = 0; j < 6; ++j) rv[j] = 0.f;  // top/bottom zero pad
        }
#pragma unroll
        for (int p = 0; p < RT; ++p) {
            if (p >= r - 2 && p <= r) {               // compile-time after unroll
                const int k = r - p;                  // tap row 0..2
#pragma unroll
                for (int kc = 0; kc < 3; ++kc) {
                    const float wv1 = a1[k * 3 + kc];
                    const float wv2 = a2[k * 3 + kc];
#pragma unroll
                    for (int j = 0; j < 4; ++j) {
                        o1[p][j] += rv[j + kc] * wv1;
                        o2[p][j] += rv[j + kc] * wv2;
                    }
                }
            }
        }
    }

    // nontemporal stores (out never re-read; don't thrash L2/L3)
    const size_t obase = (size_t)(bc * 2) * (HH * WW);   // channel 2c plane
#pragma unroll
    for (int p = 0; p < RT; ++p) {
        f32x4 s1; s1.x = o1[p][0]; s1.y = o1[p][1]; s1.z = o1[p][2]; s1.w = o1[p][3];
        f32x4 s2; s2.x = o2[p][0]; s2.y = o2[p][1]; s2.z = o2[p][2]; s2.w = o2[p][3];
        const size_t off = obase + (size_t)(h0 + p) * WW + w0;
        __builtin_nontemporal_store(s1, (f32x4*)(out + off));
        __builtin_nontemporal_store(s2, (f32x4*)(out + off + (size_t)(HH * WW)));
    }
}

extern "C" void kernel_launch(void* const* d_in, const int* in_sizes, int n_in,
                              void* d_out, int out_size, void* d_ws, size_t ws_size,
                              hipStream_t stream) {
    const float* x  = (const float*)d_in[0];
    const float* w1 = (const float*)d_in[1];
    const float* w2 = (const float*)d_in[2];
    const float* bs = (const float*)d_in[3];
    float* out = (float*)d_out;

    dwconv2_direct_kernel<<<NSEG / TPB, TPB, 0, stream>>>(x, w1, w2, bs, out);
}

// Round 2
// 216.307 us; speedup vs baseline: 1.2194x; 1.2194x over previous
//
#include <hip/hip_runtime.h>

// Depthwise 3x3 conv (stride 1, pad 1), 2 filters per input channel,
// output channels interleaved [2c, 2c+1], + bias.
// x (32,192,56,56) f32; w1,w2 (C,9); bias (2C); out (32,384,56,56).
//
// Pipelined LDS version. One block = 4 (b,c) planes sharing the same c
// (weights + halo zeroing staged ONCE per block). 784 threads = 56 rows x
// 14 float4-segments; per plane each thread does 1 coalesced float4 load,
// 4 LDS writes, an 18-float LDS stencil read, 2 contiguous-wave float4
// nontemporal stores (wave covers adjacent rows -> full-line writes, no
// write amplification -- round-1 lesson).
//
// Double-buffered LDS + RAW s_barrier with manual lgkmcnt(0): the compiler
// drains vmcnt(0) before __syncthreads(), which would serialize the
// prefetch of plane i+1 against compute of plane i. With the raw barrier
// the global load for plane i+1 stays in flight across the barrier and
// completes under plane i's stencil+stores (T14/T3 pattern).
//
// Race-freedom with ONE barrier per plane: iter i writes buf[i&1]; its
// previous readers ran in iter i-2 and must pass barrier(i-1) before any
// wave reaches iter i's writes; ds_read results are consumed (lgkm-waited)
// before that barrier. Writers drain lgkmcnt(0) before barrier(i) so
// iter i's readers see complete data.

#define BB 32
#define CC 192
#define HH 56
#define WW 56
#define W4 14
#define PITCH 60   // floats per LDS row; 60 mod 32 = 28 spreads banks per row
#define LROWS 58
#define PPB 4              // planes per block (same c, 4 consecutive-group b)
#define NGRP (BB / PPB)    // 8 b-groups

typedef float f32x4 __attribute__((ext_vector_type(4)));

__global__ __launch_bounds__(784) void dwconv2_pipe_kernel(
    const float* __restrict__ x,
    const float* __restrict__ w1,
    const float* __restrict__ w2,
    const float* __restrict__ bias,
    float* __restrict__ out)
{
    __shared__ float tile[2][LROWS * PITCH];
    __shared__ float wts[20];   // a1[9], a2[9], bias1, bias2

    const int blk = blockIdx.x;        // 0..CC*NGRP-1
    const int c   = blk % CC;
    const int b0  = (blk / CC) * PPB;  // first batch index of this block

    const int t  = threadIdx.x;        // 0..783
    const int h  = t / W4;             // image row 0..55
    const int w4 = t % W4;
    const int w0 = w4 * 4;             // image col of first output pixel

    // --- stage weights to LDS once per block (broadcast source)
    if (t < 9)        wts[t] = w1[c * 9 + t];
    else if (t < 18)  wts[t] = w2[c * 9 + (t - 9)];
    else if (t < 20)  wts[t] = bias[2 * c + (t - 18)];

    // --- zero the halo borders of BOTH buffers once per block
#pragma unroll
    for (int bf = 0; bf < 2; ++bf) {
        if (t < 60)            tile[bf][t] = 0.f;                      // row 0
        else if (t < 120)      tile[bf][57 * PITCH + (t - 60)] = 0.f;  // row 57
        else if (t < 176)      tile[bf][(t - 119) * PITCH] = 0.f;      // col 0
        else if (t < 232)      tile[bf][(t - 175) * PITCH + 57] = 0.f; // col 57
    }

    const size_t hw = (size_t)HH * WW;
    const int rowoff = h * WW + w0;

    // --- first plane load (in flight across the prologue barrier)
    f32x4 v = __builtin_nontemporal_load(
        (const f32x4*)(x + (size_t)(b0 * CC + c) * hw + rowoff));

    __syncthreads();   // full drain once per block: weights + halos visible

    // --- weights to registers (broadcast LDS reads)
    float a1[9], a2[9];
#pragma unroll
    for (int i = 0; i < 9; ++i) { a1[i] = wts[i]; a2[i] = wts[9 + i]; }
    const float bias1 = wts[18], bias2 = wts[19];

    for (int i = 0; i < PPB; ++i) {
        // --- stage plane i into buf[i&1]
        float* dst = &tile[i & 1][(h + 1) * PITCH + 1 + w0];
        dst[0] = v.x; dst[1] = v.y; dst[2] = v.z; dst[3] = v.w;

        // --- prefetch plane i+1 (stays in flight across the raw barrier)
        if (i + 1 < PPB) {
            v = __builtin_nontemporal_load(
                (const f32x4*)(x + (size_t)((b0 + i + 1) * CC + c) * hw + rowoff));
        }

        // my LDS writes complete -> visible; then block-wide raw barrier.
        asm volatile("s_waitcnt lgkmcnt(0)" ::: "memory");
        __builtin_amdgcn_s_barrier();
        __builtin_amdgcn_sched_barrier(0);
        asm volatile("" ::: "memory");

        // --- stencil from LDS: rows h..h+2, cols w0..w0+5
        float o1[4], o2[4];
#pragma unroll
        for (int p = 0; p < 4; ++p) { o1[p] = bias1; o2[p] = bias2; }

        const float* tb = tile[i & 1];
#pragma unroll
        for (int r = 0; r < 3; ++r) {
            const float* rp = &tb[(h + r) * PITCH + w0];
            float rv[6];
#pragma unroll
            for (int j = 0; j < 6; ++j) rv[j] = rp[j];
#pragma unroll
            for (int p = 0; p < 4; ++p) {
#pragma unroll
                for (int kc = 0; kc < 3; ++kc) {
                    o1[p] += rv[p + kc] * a1[r * 3 + kc];
                    o2[p] += rv[p + kc] * a2[r * 3 + kc];
                }
            }
        }

        // --- nontemporal stores; wave spans adjacent rows -> contiguous span
        const int bc = (b0 + i) * CC + c;
        const size_t obase = ((size_t)(bc * 2) * HH + h) * WW + w0;
        f32x4 s1; s1.x = o1[0]; s1.y = o1[1]; s1.z = o1[2]; s1.w = o1[3];
        f32x4 s2; s2.x = o2[0]; s2.y = o2[1]; s2.z = o2[2]; s2.w = o2[3];
        __builtin_nontemporal_store(s1, (f32x4*)(out + obase));
        __builtin_nontemporal_store(s2, (f32x4*)(out + obase + hw));
        // no trailing barrier: next iter writes buf[(i+1)&1], whose readers
        // all passed barrier(i) already (see header comment).
    }
}

extern "C" void kernel_launch(void* const* d_in, const int* in_sizes, int n_in,
                              void* d_out, int out_size, void* d_ws, size_t ws_size,
                              hipStream_t stream) {
    const float* x  = (const float*)d_in[0];
    const float* w1 = (const float*)d_in[1];
    const float* w2 = (const float*)d_in[2];
    const float* bs = (const float*)d_in[3];
    float* out = (float*)d_out;

    dwconv2_pipe_kernel<<<CC * NGRP, 784, 0, stream>>>(x, w1, w2, bs, out);
}